// Round 10
// baseline (152.907 us; speedup 1.0000x reference)
//
#include <hip/hip_runtime.h>
#include <math.h>

#define P_N 64
#define B_N 32
#define A_N 40
#define D_N 128

// ---- helpers: uniform-lane broadcast (VALU latency, not ds_bpermute) ----
__device__ __forceinline__ int readlane_i(int v, int l) {
  return __builtin_amdgcn_readlane(v, l);
}
__device__ __forceinline__ float readlane_f(float v, int l) {
  return __int_as_float(__builtin_amdgcn_readlane(__float_as_int(v), l));
}
// order-preserving float->uint map, branch-free
__device__ __forceinline__ unsigned ordf(float f) {
  unsigned b = __float_as_uint(f);
  return b ^ (((unsigned)((int)b >> 31)) | 0x80000000u);
}
// inverse of ordf (for key-derived distances)
__device__ __forceinline__ float unordf(unsigned k) {
  unsigned b = k ^ (((unsigned)((int)(~k) >> 31)) | 0x80000000u);
  return __uint_as_float(b);
}
// full-wave min via DPP (gfx9 canonical sequence), result broadcast from lane 63
__device__ __forceinline__ unsigned wave_min_u32(unsigned x) {
  unsigned t;
  t = (unsigned)__builtin_amdgcn_update_dpp((int)0xFFFFFFFFu, (int)x, 0x111, 0xF, 0xF, false); // row_shr:1
  x = t < x ? t : x;
  t = (unsigned)__builtin_amdgcn_update_dpp((int)0xFFFFFFFFu, (int)x, 0x112, 0xF, 0xF, false); // row_shr:2
  x = t < x ? t : x;
  t = (unsigned)__builtin_amdgcn_update_dpp((int)0xFFFFFFFFu, (int)x, 0x114, 0xF, 0xF, false); // row_shr:4
  x = t < x ? t : x;
  t = (unsigned)__builtin_amdgcn_update_dpp((int)0xFFFFFFFFu, (int)x, 0x118, 0xF, 0xF, false); // row_shr:8
  x = t < x ? t : x;
  t = (unsigned)__builtin_amdgcn_update_dpp((int)0xFFFFFFFFu, (int)x, 0x142, 0xA, 0xF, false); // row_bcast:15
  x = t < x ? t : x;
  t = (unsigned)__builtin_amdgcn_update_dpp((int)0xFFFFFFFFu, (int)x, 0x143, 0xC, 0xF, false); // row_bcast:31
  x = t < x ? t : x;
  return (unsigned)__builtin_amdgcn_readlane((int)x, 63);
}

// ---- 8-way constant mux (7 v_cndmask) ----
__device__ __forceinline__ float mux8(float r0, float r1, float r2, float r3,
                                      float r4, float r5, float r6, float r7, int k) {
  float a = (k & 1) ? r1 : r0;
  float b = (k & 1) ? r3 : r2;
  float c = (k & 1) ? r5 : r4;
  float d = (k & 1) ? r7 : r6;
  float e = (k & 2) ? b : a;
  float f = (k & 2) ? d : c;
  return (k & 4) ? f : e;
}

// repeat macro over the 40 named column registers
#define R40(M) M(0) M(1) M(2) M(3) M(4) M(5) M(6) M(7) M(8) M(9) \
  M(10) M(11) M(12) M(13) M(14) M(15) M(16) M(17) M(18) M(19) \
  M(20) M(21) M(22) M(23) M(24) M(25) M(26) M(27) M(28) M(29) \
  M(30) M(31) M(32) M(33) M(34) M(35) M(36) M(37) M(38) M(39)

// select c[kk] for WAVE-UNIFORM kk (scalar branch + 7 cndmask)
#define SEL40U(dst, kk) do { int _q = (kk); int _k = _q & 7;                     \
  switch (_q >> 3) {                                                             \
    case 0:  dst = mux8(c0,  c1,  c2,  c3,  c4,  c5,  c6,  c7,  _k); break;      \
    case 1:  dst = mux8(c8,  c9,  c10, c11, c12, c13, c14, c15, _k); break;      \
    case 2:  dst = mux8(c16, c17, c18, c19, c20, c21, c22, c23, _k); break;      \
    case 3:  dst = mux8(c24, c25, c26, c27, c28, c29, c30, c31, _k); break;      \
    default: dst = mux8(c32, c33, c34, c35, c36, c37, c38, c39, _k); break; }    \
  } while (0)

// select c[kk] for DIVERGENT kk (full cndmask tree, used once in epilogue)
#define SEL40D(dst, kk) do { int _q = (kk); int _k = _q & 7; int _g = _q >> 3;   \
  float _m0 = mux8(c0,  c1,  c2,  c3,  c4,  c5,  c6,  c7,  _k);                  \
  float _m1 = mux8(c8,  c9,  c10, c11, c12, c13, c14, c15, _k);                  \
  float _m2 = mux8(c16, c17, c18, c19, c20, c21, c22, c23, _k);                  \
  float _m3 = mux8(c24, c25, c26, c27, c28, c29, c30, c31, _k);                  \
  float _m4 = mux8(c32, c33, c34, c35, c36, c37, c38, c39, _k);                  \
  float _a = (_g & 1) ? _m1 : _m0; float _b = (_g & 1) ? _m3 : _m2;              \
  _a = (_g & 2) ? _b : _a; dst = (_g & 4) ? _m4 : _a; } while (0)

// one 32-dim chunk of |g*(a-b)|^2 (ap uniform across lanes -> broadcast loads)
__device__ __forceinline__ float chunk_dist(const float4* __restrict__ ap,
                                            const float4 (&gg)[8], const float4 (&bb)[8]) {
  float s = 0.f;
  #pragma unroll
  for (int k = 0; k < 8; ++k) {
    float4 a = ap[k];
    float dx = fmaf(a.x, gg[k].x, -bb[k].x); s = fmaf(dx, dx, s);
    float dy = fmaf(a.y, gg[k].y, -bb[k].y); s = fmaf(dy, dy, s);
    float dz = fmaf(a.z, gg[k].z, -bb[k].z); s = fmaf(dz, dz, s);
    float dw = fmaf(a.w, gg[k].w, -bb[k].w); s = fmaf(dw, dw, s);
  }
  return s;
}

// ---------------- Hungarian (JV) — one wave per (p,b) cost matrix ----------------
// Lane j (1..40) holds COLUMN j-1 of C in 40 NAMED scalar registers c0..c39
// (R8's array version silently went to scratch — named scalars cannot).
// No ds_read on the Dijkstra chain: register mux via scalar-branch switch
// (index is wave-uniform, from readlane). Popped distance derived from the
// packed key (truncation monotone & consistent with selection). Init =
// column reduction + col-greedy + row-pass greedy. u/v updates batched.
__global__ __launch_bounds__(64, 2) void hungarian_pair(
    const float* __restrict__ DP, const float* __restrict__ X,
    const float* __restrict__ G, float* __restrict__ out) {
  __shared__ float g_lds[D_N];
  const int bid  = blockIdx.x;
  const int lane = threadIdx.x;
  const bool realcol = (lane >= 1 && lane <= A_N);
  const int  cix     = realcol ? (lane - 1) : 0;
  const float* __restrict__ Abase = DP + (bid >> 5) * (A_N * D_N);
  const float* __restrict__ Bbase = X  + (bid & 31) * (A_N * D_N);

  // exp(gamma) once (2 expf/lane instead of 128)
  g_lds[lane]      = expf(G[lane]);
  g_lds[lane + 64] = expf(G[lane + 64]);
  __syncthreads();

  // ---- named column registers ----
#define C_DECL(n) float c##n = 0.f;
  R40(C_DECL)
#undef C_DECL

  // ---- build C[i][cix] = |g*(A_i - B_cix)|^2 into c0..c39 ----
  if (realcol) {
    const float* bp = Bbase + cix * D_N;
    for (int c = 0; c < 4; ++c) {                   // 4 chunks of 32 dims
      float4 gg[8], bb[8];
      #pragma unroll
      for (int k = 0; k < 8; ++k) {
        gg[k] = ((const float4*)(g_lds + c * 32))[k];        // uniform LDS broadcast
        float4 br = ((const float4*)(bp + c * 32))[k];
        bb[k] = make_float4(br.x * gg[k].x, br.y * gg[k].y,
                            br.z * gg[k].z, br.w * gg[k].w);
      }
#define BROW(n) c##n += chunk_dist((const float4*)(Abase + n * D_N + c * 32), gg, bb);
      R40(BROW)
#undef BROW
    }
  }

  // ---- column reduction: v[j] = min_i C[i][j], remember argmin row ----
  float vpot = 0.f;
  int   amin = 0;                        // 1-based argmin row for this column
  if (realcol) {
    float mn = c0; int mi = 0;
#define CMIN(n) if (c##n < mn) { mn = c##n; mi = n; }
    R40(CMIN)
#undef CMIN
    vpot = mn; amin = mi + 1;
  }

  // ---- greedy pass 1: column argmins on tight edges (u=0, v=colmin) ----
  unsigned long long rmask = 0ull;       // bit r = row r matched (uniform across lanes)
  int p = 0, way = 0;                    // p: row matched to this column (0 = free)
  for (int j = 1; j <= A_N; ++j) {
    int am = readlane_i(amin, j);
    if (!((rmask >> am) & 1ull)) {
      rmask |= 1ull << am;
      if (lane == j) p = am;
    }
  }

  float u = 0.f;                         // row potential (lane = row 1..40)

  // ---- greedy pass 2 (row pass): assign free rows on free argmin cols only ----
  for (int i = 1; i <= A_N; ++i) {
    if ((rmask >> i) & 1ull) continue;
    float r = INFINITY;
    if (realcol) { float cv; SEL40U(cv, i - 1); r = cv - vpot; }
    unsigned key = (ordf(r) & 0xFFFFFFC0u) | (unsigned)lane;
    unsigned kmin = wave_min_u32(key);
    int jm = (int)(kmin & 63u);
    int pj = readlane_i(p, jm);
    if (pj == 0) {                        // argmin column free -> assign tight edge
      float rmin = readlane_f(r, jm);
      if (lane == jm) p = i;
      if (lane == i)  u = rmin;
      rmask |= 1ull << i;
    }
  }

  // ---- shortest augmenting path for remaining free rows (deferred potentials) ----
  for (int f = 1; f <= A_N; ++f) {
    if ((rmask >> f) & 1ull) continue;   // matched — skip (wave-uniform)
    if (lane == 0) p = f;                // p[0] = f  (augmentation reads this!)
    float mhat = INFINITY;               // min_i (A_j(i) + Dsum_entry(i))
    float excl = realcol ? 0.f : INFINITY; // +INF once this column leaves the frontier
    float dsum = 0.f;                    // accumulated delta (current Dijkstra radius)
    float dent = 0.f, rent = 0.f;        // Dsum when this col became used / row entered
    bool  used   = !realcol;
    bool  intree = (lane == f);
    int   j0 = 0, i0 = f;
    const unsigned plane_key = ((unsigned)p << 6) | (unsigned)lane; // p static in-search
    for (int guard = 0; guard < 42; ++guard) {
      float Craw; SEL40U(Craw, i0 - 1);             // register mux — no LDS on chain
      float uc   = readlane_f(u, i0);
      float off  = dsum - uc - vpot + excl;         // INF if excluded
      float cand = Craw + off;
      if (cand < mhat) way = j0;                    // off-chain cndmask
      mhat = fminf(mhat, cand);
      unsigned key = (ordf(mhat) & 0xFFFFF000u) | plane_key;
      unsigned kmin = wave_min_u32(key);
      int j1 = (int)(kmin & 63u);
      int i1 = (int)((kmin >> 6) & 63u);            // p[j1] from the key — no readlane
      float dnew = unordf(kmin & 0xFFFFF000u);      // popped distance from the key
      if (lane == j1) { used = true; dent = dnew; excl = INFINITY; mhat = INFINITY; }
      dsum = dnew;
      j0 = j1;
      i0 = i1;
      if (i1 == 0) break;                           // free column reached
      if (lane == i1) { intree = true; rent = dnew; }
    }
    // batched potential updates: v[j] -= (Dfinal - Dent_j), u[i] += (Dfinal - Rent_i)
    if (used && realcol) vpot -= (dsum - dent);
    if (intree)          u    += (dsum - rent);
    // augment along way[] back to the dummy column
    while (j0 != 0) {
      int jn = readlane_i(way, j0);
      int pn = readlane_i(p, jn);
      if (lane == j0) p = pn;
      j0 = jn;
    }
  }

  // ---- matched-kernel value: sum_j exp(-C[p[j]-1][j-1]) / 40 ----
  int pk = realcol ? (p - 1) : 0;        // divergent index
  float cm; SEL40D(cm, pk);
  float e = realcol ? expf(-cm) : 0.f;
  #pragma unroll
  for (int off = 32; off; off >>= 1) e += __shfl_xor(e, off);
  if (lane == 0) out[bid] = e / 40.0f;
}

// ---------------- mean + triangular solve + var (kxx == 1.0, see note) ----------------
// Self-distance diagonal is |v-v|^2 = 0 (ref: abs(-2*dot+s+s) ~ 1e-6), Hungarian on it
// is identity, so kxx = sum(exp(-~0))/40 = 1 - O(1e-6). Hard-code 1.0f.
// Forward substitution fully unrolled; per-thread solve vector in registers.
__global__ __launch_bounds__(64) void final_kernel(
    const float* __restrict__ Kx, const float* __restrict__ L,
    const float* __restrict__ alpha, float* __restrict__ out) {
  int b = threadIdx.x;
  if (b >= B_N) return;
  float mean = 0.f;
  #pragma unroll
  for (int p = 0; p < P_N; ++p) mean = fmaf(Kx[p * B_N + b], alpha[p], mean);
  out[b] = mean;
  float vr[P_N];
  float sumv2 = 0.f;
  #pragma unroll
  for (int i = 0; i < P_N; ++i) {
    float s = Kx[i * B_N + b];
    #pragma unroll
    for (int j = 0; j < i; ++j) s = fmaf(-L[i * P_N + j], vr[j], s);
    float vi = s / L[i * P_N + i];
    vr[i] = vi;
    sumv2 = fmaf(vi, vi, sumv2);
  }
  out[B_N + b] = 1.0f - sumv2;
}

extern "C" void kernel_launch(void* const* d_in, const int* in_sizes, int n_in,
                              void* d_out, int out_size, void* d_ws, size_t ws_size,
                              hipStream_t stream) {
  const float* x     = (const float*)d_in[0];   // [32,40,128]
  const float* dp    = (const float*)d_in[1];   // [64,40,128]
  const float* gamma = (const float*)d_in[2];   // [1,128]
  const float* L     = (const float*)d_in[3];   // [64,64]
  const float* alpha = (const float*)d_in[4];   // [64]
  float* out = (float*)d_out;                   // mean[32] ++ var[32]

  float* Kx = (float*)d_ws;                     // 2048 f32

  hungarian_pair<<<P_N * B_N, 64, 0, stream>>>(dp, x, gamma, Kx);
  final_kernel<<<1, 64, 0, stream>>>(Kx, L, alpha, out);
}

// Round 11
// 127.592 us; speedup vs baseline: 1.1984x; 1.1984x over previous
//
#include <hip/hip_runtime.h>
#include <math.h>

#define P_N 64
#define B_N 32
#define A_N 40
#define D_N 128

// ---- helpers: uniform-lane broadcast (VALU latency, not ds_bpermute) ----
__device__ __forceinline__ int readlane_i(int v, int l) {
  return __builtin_amdgcn_readlane(v, l);
}
__device__ __forceinline__ float readlane_f(float v, int l) {
  return __int_as_float(__builtin_amdgcn_readlane(__float_as_int(v), l));
}
// order-preserving float->uint map, branch-free; bijective (monotone both ways)
__device__ __forceinline__ unsigned ordf(float f) {
  unsigned b = __float_as_uint(f);
  return b ^ (((unsigned)((int)b >> 31)) | 0x80000000u);
}
// inverse of ordf (for key-derived values; masking low bits rounds DOWN)
__device__ __forceinline__ float unordf(unsigned k) {
  unsigned b = k ^ (((unsigned)((int)(~k) >> 31)) | 0x80000000u);
  return __uint_as_float(b);
}
// full-wave min via DPP (gfx9 canonical sequence), result broadcast from lane 63
__device__ __forceinline__ unsigned wave_min_u32(unsigned x) {
  unsigned t;
  t = (unsigned)__builtin_amdgcn_update_dpp((int)0xFFFFFFFFu, (int)x, 0x111, 0xF, 0xF, false); // row_shr:1
  x = t < x ? t : x;
  t = (unsigned)__builtin_amdgcn_update_dpp((int)0xFFFFFFFFu, (int)x, 0x112, 0xF, 0xF, false); // row_shr:2
  x = t < x ? t : x;
  t = (unsigned)__builtin_amdgcn_update_dpp((int)0xFFFFFFFFu, (int)x, 0x114, 0xF, 0xF, false); // row_shr:4
  x = t < x ? t : x;
  t = (unsigned)__builtin_amdgcn_update_dpp((int)0xFFFFFFFFu, (int)x, 0x118, 0xF, 0xF, false); // row_shr:8
  x = t < x ? t : x;
  t = (unsigned)__builtin_amdgcn_update_dpp((int)0xFFFFFFFFu, (int)x, 0x142, 0xA, 0xF, false); // row_bcast:15
  x = t < x ? t : x;
  t = (unsigned)__builtin_amdgcn_update_dpp((int)0xFFFFFFFFu, (int)x, 0x143, 0xC, 0xF, false); // row_bcast:31
  x = t < x ? t : x;
  return (unsigned)__builtin_amdgcn_readlane((int)x, 63);
}
// full-wave (min, 2nd-min) pair reduce over u32 keys; both broadcast from lane 63
__device__ __forceinline__ void wave_min2_u32(unsigned x, unsigned &m1o, unsigned &m2o) {
  unsigned m1 = x, m2 = 0xFFFFFFFFu;
  unsigned t1, t2, lo, hi;
#define MIN2_STAGE(ctrl, rm) \
  t1 = (unsigned)__builtin_amdgcn_update_dpp((int)0xFFFFFFFFu, (int)m1, ctrl, rm, 0xF, false); \
  t2 = (unsigned)__builtin_amdgcn_update_dpp((int)0xFFFFFFFFu, (int)m2, ctrl, rm, 0xF, false); \
  lo = m1 < t1 ? m1 : t1; hi = m1 < t1 ? t1 : m1;                                              \
  m2 = m2 < t2 ? m2 : t2; m2 = m2 < hi ? m2 : hi; m1 = lo;
  MIN2_STAGE(0x111, 0xF)   // row_shr:1
  MIN2_STAGE(0x112, 0xF)   // row_shr:2
  MIN2_STAGE(0x114, 0xF)   // row_shr:4
  MIN2_STAGE(0x118, 0xF)   // row_shr:8
  MIN2_STAGE(0x142, 0xA)   // row_bcast:15
  MIN2_STAGE(0x143, 0xC)   // row_bcast:31
#undef MIN2_STAGE
  m1o = (unsigned)__builtin_amdgcn_readlane((int)m1, 63);
  m2o = (unsigned)__builtin_amdgcn_readlane((int)m2, 63);
}

// ---------------- Hungarian (JV) — one wave per (p,b) cost matrix ----------------
// Lane j = column j (0 = dummy, 1..40 real). Lane r also holds row-potential u[r].
// Build fuses gamma scaling (exp(gamma) staged once in LDS). Init = column
// reduction + col-greedy + CLASSICAL JV augmenting row reduction (ARR): per free
// row, (u1,j1)=min, u2=2nd-min of C[I][j]-v[j]; set u[I]=u2, v[j1]-=(u2-u1)
// (keeps (I,j1) tight, all slacks >= 0 — u2 floored by key truncation only
// rounds DOWN, preserving admissibility), assign, displaced owner continues the
// chain. Exact ties on owned cols defer to Dijkstra; 64-iter cap bounds
// pathologies. Search = R9's deferred-potential Dijkstra (verified).
__global__ __launch_bounds__(64) void hungarian_pair(
    const float* __restrict__ DP, const float* __restrict__ X,
    const float* __restrict__ G, float* __restrict__ out) {
  __shared__ float Cs[A_N * A_N];
  __shared__ float g_lds[D_N];
  const int bid  = blockIdx.x;
  const int lane = threadIdx.x;
  const float* __restrict__ Abase = DP + (bid >> 5) * (A_N * D_N);
  const float* __restrict__ Bbase = X  + (bid & 31) * (A_N * D_N);

  // exp(gamma) once (2 expf/lane instead of 128)
  g_lds[lane]      = expf(G[lane]);
  g_lds[lane + 64] = expf(G[lane + 64]);
  __syncthreads();

  // ---- build C[i][j] = |g*(A_i - B_j)|^2 ; lane j owns column j ----
  if (lane < A_N) {
    const float* bp = Bbase + lane * D_N;
    for (int c = 0; c < 4; ++c) {                   // 4 chunks of 32 dims
      float4 gg[8], bb[8];
      #pragma unroll
      for (int k = 0; k < 8; ++k) {
        gg[k] = ((const float4*)(g_lds + c * 32))[k];        // uniform LDS -> broadcast
        float4 br = ((const float4*)(bp + c * 32))[k];
        bb[k] = make_float4(br.x * gg[k].x, br.y * gg[k].y,
                            br.z * gg[k].z, br.w * gg[k].w);
      }
      for (int i = 0; i < A_N; ++i) {
        const float4* ap = (const float4*)(Abase + i * D_N + c * 32); // uniform -> broadcast
        float s = 0.f;
        #pragma unroll
        for (int k = 0; k < 8; ++k) {
          float4 a = ap[k];
          float dx = fmaf(a.x, gg[k].x, -bb[k].x); s = fmaf(dx, dx, s);
          float dy = fmaf(a.y, gg[k].y, -bb[k].y); s = fmaf(dy, dy, s);
          float dz = fmaf(a.z, gg[k].z, -bb[k].z); s = fmaf(dz, dz, s);
          float dw = fmaf(a.w, gg[k].w, -bb[k].w); s = fmaf(dw, dw, s);
        }
        if (c == 0) Cs[i * A_N + lane] = s;
        else        Cs[i * A_N + lane] += s;
      }
    }
  }
  __syncthreads();

  const int  cix     = (lane >= 1 && lane <= A_N) ? (lane - 1) : 0;
  const bool realcol = (lane >= 1 && lane <= A_N);

  // ---- column reduction: v[j] = min_i C[i][j], remember argmin row ----
  float vpot = 0.f;
  int   amin = 0;                        // 1-based argmin row for this column
  if (realcol) {
    float mn = INFINITY; int mi = 0;
    for (int i = 0; i < A_N; ++i) {
      float c = Cs[i * A_N + cix];
      if (c < mn) { mn = c; mi = i; }
    }
    vpot = mn; amin = mi + 1;
  }

  // ---- greedy pass 1: column argmins on tight edges (u=0, v=colmin) ----
  unsigned long long rmask = 0ull;       // bit r = row r matched (uniform across lanes)
  int p = 0, way = 0;                    // p: row matched to this column (0 = free)
  for (int j = 1; j <= A_N; ++j) {
    int am = readlane_i(amin, j);
    if (!((rmask >> am) & 1ull)) {
      rmask |= 1ull << am;
      if (lane == j) p = am;
    }
  }

  float u = 0.f;                         // row potential (lane = row 1..40)

  // ---- JV augmenting row reduction (with steal chains) ----
  unsigned long long fmask = (((1ull << (A_N + 1)) - 2ull)) & ~rmask; // free rows 1..40
  unsigned long long dmask = 0ull;       // rows deferred to Dijkstra
  {
    int I = 0; bool chaining = false; int iters = 0;
    while ((chaining || fmask) && iters < 64) {
      if (!chaining) { I = __builtin_ctzll(fmask); fmask &= fmask - 1ull; }
      ++iters;
      float r = realcol ? (Cs[(I - 1) * A_N + cix] - vpot) : INFINITY;
      unsigned key = (ordf(r) & 0xFFFFFFC0u) | (unsigned)lane;
      unsigned m1, m2;
      wave_min2_u32(key, m1, m2);
      int   j1  = (int)(m1 & 63u);
      float u1  = readlane_f(r, j1);          // exact min
      float u2a = unordf(m2 & 0xFFFFFFC0u);   // 2nd-min, floored (admissible)
      int   k   = readlane_i(p, j1);          // current owner of j1 (0 = free)
      bool  strict = (u1 < u2a);
      if (strict || k == 0) {
        if (strict) {
          if (lane == j1) vpot -= (u2a - u1); // (I,j1) becomes tight at u2a
          if (lane == I)  u = u2a;
        } else {
          if (lane == I)  u = u1;             // free col, tie: tight at u1
        }
        if (lane == j1) p = I;                // assign I -> j1
        if (k != 0) { I = k; chaining = true; }   // displaced owner continues
        else        chaining = false;
      } else {
        dmask |= 1ull << I;                   // tie on owned col -> Dijkstra
        chaining = false;
      }
    }
    if (chaining) dmask |= 1ull << I;         // cap hit mid-chain
    dmask |= fmask;                           // unprocessed rows (cap)
  }

  // ---- shortest augmenting path for remaining free rows (deferred potentials) ----
  while (dmask) {
    int f = __builtin_ctzll(dmask); dmask &= dmask - 1ull;
    if (lane == 0) p = f;                // p[0] = f  (augmentation reads this!)
    float mhat = INFINITY;               // min_i (A_j(i) + Dsum_entry(i))
    float excl = realcol ? 0.f : INFINITY; // +INF once this column leaves the frontier
    float dsum = 0.f;                    // accumulated delta (current Dijkstra radius)
    float dent = 0.f, rent = 0.f;        // Dsum when this col became used / row entered
    bool  used   = !realcol;
    bool  intree = (lane == f);
    int   j0 = 0, i0 = f;
    const unsigned plane_key = ((unsigned)p << 6) | (unsigned)lane; // p static in-search
    for (int guard = 0; guard < 42; ++guard) {
      float Craw = Cs[(i0 - 1) * A_N + cix];        // ds_read issues first
      float uc   = readlane_f(u, i0);               // overlaps LDS latency
      float off  = dsum - uc - vpot + excl;         // load-shadow; INF if excluded
      float cand = Craw + off;                      // 1 VALU after load
      if (cand < mhat) way = j0;                    // off-chain cndmask
      mhat = fminf(mhat, cand);
      unsigned key = (ordf(mhat) & 0xFFFFF000u) | plane_key;
      unsigned kmin = wave_min_u32(key);
      int j1 = (int)(kmin & 63u);
      int i1 = (int)((kmin >> 6) & 63u);            // p[j1] from the key — no readlane
      float dnew = unordf(kmin & 0xFFFFF000u);      // popped distance from the key
      if (lane == j1) { used = true; dent = dnew; excl = INFINITY; mhat = INFINITY; }
      dsum = dnew;
      j0 = j1;
      i0 = i1;
      if (i1 == 0) break;                           // free column reached
      if (lane == i1) { intree = true; rent = dnew; }
    }
    // batched potential updates: v[j] -= (Dfinal - Dent_j), u[i] += (Dfinal - Rent_i)
    if (used && realcol) vpot -= (dsum - dent);
    if (intree)          u    += (dsum - rent);
    // augment along way[] back to the dummy column
    while (j0 != 0) {
      int jn = readlane_i(way, j0);
      int pn = readlane_i(p, jn);
      if (lane == j0) p = pn;
      j0 = jn;
    }
  }

  // ---- matched-kernel value: sum_j exp(-C[p[j]-1][j-1]) / 40 ----
  float e = 0.f;
  if (realcol) e = expf(-Cs[(p - 1) * A_N + (lane - 1)]);
  #pragma unroll
  for (int off = 32; off; off >>= 1) e += __shfl_xor(e, off);
  if (lane == 0) out[bid] = e / 40.0f;
}

// ---------------- mean + triangular solve + var (kxx == 1.0, see note) ----------------
// Self-distance diagonal is |v-v|^2 = 0 (ref: abs(-2*dot+s+s) ~ 1e-6), Hungarian on it
// is identity, so kxx = sum(exp(-~0))/40 = 1 - O(1e-6). Hard-code 1.0f.
// Forward substitution fully unrolled; per-thread solve vector in registers.
__global__ __launch_bounds__(64) void final_kernel(
    const float* __restrict__ Kx, const float* __restrict__ L,
    const float* __restrict__ alpha, float* __restrict__ out) {
  int b = threadIdx.x;
  if (b >= B_N) return;
  float mean = 0.f;
  #pragma unroll
  for (int p = 0; p < P_N; ++p) mean = fmaf(Kx[p * B_N + b], alpha[p], mean);
  out[b] = mean;
  float vr[P_N];
  float sumv2 = 0.f;
  #pragma unroll
  for (int i = 0; i < P_N; ++i) {
    float s = Kx[i * B_N + b];
    #pragma unroll
    for (int j = 0; j < i; ++j) s = fmaf(-L[i * P_N + j], vr[j], s);
    float vi = s / L[i * P_N + i];
    vr[i] = vi;
    sumv2 = fmaf(vi, vi, sumv2);
  }
  out[B_N + b] = 1.0f - sumv2;
}

extern "C" void kernel_launch(void* const* d_in, const int* in_sizes, int n_in,
                              void* d_out, int out_size, void* d_ws, size_t ws_size,
                              hipStream_t stream) {
  const float* x     = (const float*)d_in[0];   // [32,40,128]
  const float* dp    = (const float*)d_in[1];   // [64,40,128]
  const float* gamma = (const float*)d_in[2];   // [1,128]
  const float* L     = (const float*)d_in[3];   // [64,64]
  const float* alpha = (const float*)d_in[4];   // [64]
  float* out = (float*)d_out;                   // mean[32] ++ var[32]

  float* Kx = (float*)d_ws;                     // 2048 f32

  hungarian_pair<<<P_N * B_N, 64, 0, stream>>>(dp, x, gamma, Kx);
  final_kernel<<<1, 64, 0, stream>>>(Kx, L, alpha, out);
}